// Round 1
// baseline (312.611 us; speedup 1.0000x reference)
//
#include <hip/hip_runtime.h>

#define B_    512
#define IN_   256
#define H_    512
#define OUT_  64
#define NDEATH (B_ - 1)
#define RTOL_ 1e-6
#define ATOL_ 1e-8

// ---------------------------------------------------------------------------
// init: tolerance windows per death + zero accumulators
// acc[0]=homology_sum, acc[1]=target_sq_sum, acc[2]=compactness_sum
// ---------------------------------------------------------------------------
__global__ void init_k(const float* __restrict__ deaths,
                       double* __restrict__ lo, double* __restrict__ hi,
                       double* __restrict__ acc) {
    int t = blockIdx.x * blockDim.x + threadIdx.x;
    if (t < NDEATH) {
        double d = (double)deaths[t];
        double w = ATOL_ + RTOL_ * fabs(d);
        lo[t] = d - w;
        hi[t] = d + w;
    }
    if (t < 3) acc[t] = 0.0;
}

// ---------------------------------------------------------------------------
// Tiled f64 GEMM:  C[M,N] = act(A[M,K] @ W[K,N] + bias[N])
// A is f32 (layer 1) or f64 (later layers); W,bias f32; C f64.
// Block (16,16) computes a 32x32 output tile, 2x2 per thread, K-tile 16.
// ---------------------------------------------------------------------------
template <typename TIN, bool RELU>
__global__ __launch_bounds__(256) void gemm_k(const TIN* __restrict__ A,
                                              const float* __restrict__ W,
                                              const float* __restrict__ bias,
                                              double* __restrict__ C,
                                              int M, int N, int K) {
    __shared__ double As[16][33];  // [kk][mm]
    __shared__ double Ws[16][33];  // [kk][nn]
    const int tx = threadIdx.x, ty = threadIdx.y;
    const int row0 = blockIdx.y * 32, col0 = blockIdx.x * 32;

    double acc00 = 0.0, acc01 = 0.0, acc10 = 0.0, acc11 = 0.0;

    for (int k0 = 0; k0 < K; k0 += 16) {
        // stage A tile: As[kk=tx][mm=2*ty+p]
        #pragma unroll
        for (int p = 0; p < 2; ++p) {
            int mm = 2 * ty + p;
            As[tx][mm] = (double)A[(size_t)(row0 + mm) * K + k0 + tx];
        }
        // stage W tile: Ws[kk=ty][nn=tx+16p]
        #pragma unroll
        for (int p = 0; p < 2; ++p) {
            int nn = tx + 16 * p;
            Ws[ty][nn] = (double)W[(size_t)(k0 + ty) * N + col0 + nn];
        }
        __syncthreads();
        #pragma unroll
        for (int kk = 0; kk < 16; ++kk) {
            double a0 = As[kk][ty];
            double a1 = As[kk][ty + 16];
            double b0 = Ws[kk][tx];
            double b1 = Ws[kk][tx + 16];
            acc00 = fma(a0, b0, acc00);
            acc01 = fma(a0, b1, acc01);
            acc10 = fma(a1, b0, acc10);
            acc11 = fma(a1, b1, acc11);
        }
        __syncthreads();
    }

    double accs[2][2] = {{acc00, acc01}, {acc10, acc11}};
    #pragma unroll
    for (int p = 0; p < 2; ++p) {
        #pragma unroll
        for (int q = 0; q < 2; ++q) {
            int r = row0 + ty + 16 * p;
            int c = col0 + tx + 16 * q;
            double v = accs[p][q] + (double)bias[c];
            if (RELU) v = v > 0.0 ? v : 0.0;
            C[(size_t)r * N + c] = v;
        }
    }
}

// ---------------------------------------------------------------------------
// column means of y [B_, OUT_]: one block (1 wave) per column
// ---------------------------------------------------------------------------
__global__ void colmean_k(const double* __restrict__ y, double* __restrict__ cm) {
    int c = blockIdx.x;
    int t = threadIdx.x;  // 64 threads = 1 wave
    double s = 0.0;
    for (int r = t; r < B_; r += 64) s += y[(size_t)r * OUT_ + c];
    for (int off = 32; off; off >>= 1) s += __shfl_down(s, off);
    if (t == 0) cm[c] = s / (double)B_;
}

// ---------------------------------------------------------------------------
// fused target-MSE-sum + compactness-sum over the 512x64 y matrix
// ---------------------------------------------------------------------------
__global__ __launch_bounds__(256) void tc_k(const float* __restrict__ target,
                                            const double* __restrict__ y,
                                            const double* __restrict__ cm,
                                            double* __restrict__ acc) {
    int i = blockIdx.x * 256 + threadIdx.x;  // 128*256 == B_*OUT_ exactly
    double yv = y[i];
    double d = (double)target[i] - yv;
    double t_s = d * d;
    double c_s = fabs(yv - cm[i & (OUT_ - 1)]);

    for (int off = 32; off; off >>= 1) {
        t_s += __shfl_down(t_s, off);
        c_s += __shfl_down(c_s, off);
    }
    __shared__ double st[4], sc[4];
    int wave = threadIdx.x >> 6, lane = threadIdx.x & 63;
    if (lane == 0) { st[wave] = t_s; sc[wave] = c_s; }
    __syncthreads();
    if (threadIdx.x == 0) {
        atomicAdd(&acc[1], st[0] + st[1] + st[2] + st[3]);
        atomicAdd(&acc[2], sc[0] + sc[1] + sc[2] + sc[3]);
    }
}

// ---------------------------------------------------------------------------
// pdist + isclose-any match + homology sum. Block i handles pairs (i, j>i).
// Death windows cached in LDS; early-exit linear scan.
// ---------------------------------------------------------------------------
__global__ __launch_bounds__(256) void pdist_k(const double* __restrict__ y,
                                               const double* __restrict__ lo,
                                               const double* __restrict__ hi,
                                               double* __restrict__ acc) {
    int i = blockIdx.x;  // 0..B_-2
    int t = threadIdx.x;
    __shared__ double yi[OUT_];
    __shared__ double slo[NDEATH], shi[NDEATH];
    if (t < OUT_) yi[t] = y[(size_t)i * OUT_ + t];
    for (int k = t; k < NDEATH; k += 256) { slo[k] = lo[k]; shi[k] = hi[k]; }
    __syncthreads();

    double local = 0.0;
    for (int j = i + 1 + t; j < B_; j += 256) {
        const double* yj = y + (size_t)j * OUT_;
        double s = 0.0;
        #pragma unroll
        for (int d = 0; d < OUT_; ++d) {
            double df = yi[d] - yj[d];
            s = fma(df, df, s);
        }
        double pd = sqrt(s);
        bool m = false;
        for (int k = 0; k < NDEATH; ++k) {
            if (pd >= slo[k] && pd <= shi[k]) { m = true; break; }
        }
        if (m) local += pd;
    }

    double v = local;
    for (int off = 32; off; off >>= 1) v += __shfl_down(v, off);
    __shared__ double sw[4];
    int wave = t >> 6, lane = t & 63;
    if (lane == 0) sw[wave] = v;
    __syncthreads();
    if (t == 0) {
        double s = sw[0] + sw[1] + sw[2] + sw[3];
        if (s != 0.0) atomicAdd(&acc[0], s);
    }
}

// ---------------------------------------------------------------------------
// finalize: loss = mean_sq + hom + 0.01*compact
// ---------------------------------------------------------------------------
__global__ void fin_k(const double* __restrict__ acc, float* __restrict__ out) {
    out[0] = (float)(acc[1] / (double)(B_ * OUT_) + acc[0] + 0.01 * acc[2]);
}

extern "C" void kernel_launch(void* const* d_in, const int* in_sizes, int n_in,
                              void* d_out, int out_size, void* d_ws, size_t ws_size,
                              hipStream_t stream) {
    const float* batch  = (const float*)d_in[0];
    const float* target = (const float*)d_in[1];
    const float* W1     = (const float*)d_in[2];
    const float* b1     = (const float*)d_in[3];
    const float* W2     = (const float*)d_in[4];
    const float* b2     = (const float*)d_in[5];
    const float* W3     = (const float*)d_in[6];
    const float* b3     = (const float*)d_in[7];
    const float* Wout   = (const float*)d_in[8];
    const float* bout   = (const float*)d_in[9];
    const float* deaths = (const float*)d_in[10];
    float* out = (float*)d_out;

    double* hA  = (double*)d_ws;            // 512*512
    double* hB  = hA + (size_t)B_ * H_;     // 512*512
    double* yv  = hB + (size_t)B_ * H_;     // 512*64
    double* cm  = yv + (size_t)B_ * OUT_;   // 64
    double* lo  = cm + OUT_;                // 511
    double* hi  = lo + NDEATH;              // 511
    double* acc = hi + NDEATH;              // 3

    init_k<<<dim3(1), dim3(512), 0, stream>>>(deaths, lo, hi, acc);

    dim3 blk(16, 16);
    gemm_k<float, true><<<dim3(H_ / 32, B_ / 32), blk, 0, stream>>>(
        batch, W1, b1, hA, B_, H_, IN_);
    gemm_k<double, true><<<dim3(H_ / 32, B_ / 32), blk, 0, stream>>>(
        hA, W2, b2, hB, B_, H_, H_);
    gemm_k<double, true><<<dim3(H_ / 32, B_ / 32), blk, 0, stream>>>(
        hB, W3, b3, hA, B_, H_, H_);
    gemm_k<double, false><<<dim3(OUT_ / 32, B_ / 32), blk, 0, stream>>>(
        hA, Wout, bout, yv, B_, OUT_, H_);

    colmean_k<<<dim3(OUT_), dim3(64), 0, stream>>>(yv, cm);
    tc_k<<<dim3((B_ * OUT_) / 256), dim3(256), 0, stream>>>(target, yv, cm, acc);
    pdist_k<<<dim3(B_ - 1), dim3(256), 0, stream>>>(yv, lo, hi, acc);
    fin_k<<<dim3(1), dim3(1), 0, stream>>>(acc, out);
}

// Round 2
// 215.297 us; speedup vs baseline: 1.4520x; 1.4520x over previous
//
#include <hip/hip_runtime.h>

#define B_    512
#define IN_   256
#define H_    512
#define OUT_  64
#define NDEATH (B_ - 1)
#define NSORT  512          // NDEATH padded to pow2 for bitonic sort / bsearch
#define RTOL_ 1e-6
#define ATOL_ 1e-8

// ---------------------------------------------------------------------------
// init: bitonic-sort the deaths (1 block, 512 threads), emit SORTED tolerance
// windows lo/hi (both strictly increasing in d since width = atol+rtol*d),
// pad with +huge. Zero accumulators.
// acc[0]=homology_sum, acc[1]=target_sq_sum, acc[2]=compactness_sum
// ---------------------------------------------------------------------------
__global__ __launch_bounds__(NSORT) void init_k(const float* __restrict__ deaths,
                                                double* __restrict__ lo,
                                                double* __restrict__ hi,
                                                double* __restrict__ acc) {
    __shared__ double sd[NSORT];
    const int t = threadIdx.x;
    sd[t] = (t < NDEATH) ? (double)deaths[t] : 1e300;
    __syncthreads();
    for (int k = 2; k <= NSORT; k <<= 1) {
        for (int j = k >> 1; j > 0; j >>= 1) {
            int ixj = t ^ j;
            if (ixj > t) {
                double a = sd[t], b = sd[ixj];
                bool up = ((t & k) == 0);
                if ((a > b) == up) { sd[t] = b; sd[ixj] = a; }
            }
            __syncthreads();
        }
    }
    double d = sd[t];
    double w = ATOL_ + RTOL_ * fabs(d);
    lo[t] = d - w;
    hi[t] = d + w;
    if (t < 3) acc[t] = 0.0;
}

// ---------------------------------------------------------------------------
// Tiled f64 GEMM:  C[M,N] = act(A[M,K] @ W[K,N] + bias[N])   (unchanged R1)
// ---------------------------------------------------------------------------
template <typename TIN, bool RELU>
__global__ __launch_bounds__(256) void gemm_k(const TIN* __restrict__ A,
                                              const float* __restrict__ W,
                                              const float* __restrict__ bias,
                                              double* __restrict__ C,
                                              int M, int N, int K) {
    __shared__ double As[16][33];  // [kk][mm]
    __shared__ double Ws[16][33];  // [kk][nn]
    const int tx = threadIdx.x, ty = threadIdx.y;
    const int row0 = blockIdx.y * 32, col0 = blockIdx.x * 32;

    double acc00 = 0.0, acc01 = 0.0, acc10 = 0.0, acc11 = 0.0;

    for (int k0 = 0; k0 < K; k0 += 16) {
        #pragma unroll
        for (int p = 0; p < 2; ++p) {
            int mm = 2 * ty + p;
            As[tx][mm] = (double)A[(size_t)(row0 + mm) * K + k0 + tx];
        }
        #pragma unroll
        for (int p = 0; p < 2; ++p) {
            int nn = tx + 16 * p;
            Ws[ty][nn] = (double)W[(size_t)(k0 + ty) * N + col0 + nn];
        }
        __syncthreads();
        #pragma unroll
        for (int kk = 0; kk < 16; ++kk) {
            double a0 = As[kk][ty];
            double a1 = As[kk][ty + 16];
            double b0 = Ws[kk][tx];
            double b1 = Ws[kk][tx + 16];
            acc00 = fma(a0, b0, acc00);
            acc01 = fma(a0, b1, acc01);
            acc10 = fma(a1, b0, acc10);
            acc11 = fma(a1, b1, acc11);
        }
        __syncthreads();
    }

    double accs[2][2] = {{acc00, acc01}, {acc10, acc11}};
    #pragma unroll
    for (int p = 0; p < 2; ++p) {
        #pragma unroll
        for (int q = 0; q < 2; ++q) {
            int r = row0 + ty + 16 * p;
            int c = col0 + tx + 16 * q;
            double v = accs[p][q] + (double)bias[c];
            if (RELU) v = v > 0.0 ? v : 0.0;
            C[(size_t)r * N + c] = v;
        }
    }
}

// ---------------------------------------------------------------------------
// column means of y [B_, OUT_]: one block (1 wave) per column
// ---------------------------------------------------------------------------
__global__ void colmean_k(const double* __restrict__ y, double* __restrict__ cm) {
    int c = blockIdx.x;
    int t = threadIdx.x;  // 64 threads = 1 wave
    double s = 0.0;
    for (int r = t; r < B_; r += 64) s += y[(size_t)r * OUT_ + c];
    for (int off = 32; off; off >>= 1) s += __shfl_down(s, off);
    if (t == 0) cm[c] = s / (double)B_;
}

// ---------------------------------------------------------------------------
// fused target-MSE-sum + compactness-sum over the 512x64 y matrix
// ---------------------------------------------------------------------------
__global__ __launch_bounds__(256) void tc_k(const float* __restrict__ target,
                                            const double* __restrict__ y,
                                            const double* __restrict__ cm,
                                            double* __restrict__ acc) {
    int i = blockIdx.x * 256 + threadIdx.x;  // 128*256 == B_*OUT_ exactly
    double yv = y[i];
    double d = (double)target[i] - yv;
    double t_s = d * d;
    double c_s = fabs(yv - cm[i & (OUT_ - 1)]);

    for (int off = 32; off; off >>= 1) {
        t_s += __shfl_down(t_s, off);
        c_s += __shfl_down(c_s, off);
    }
    __shared__ double st[4], sc[4];
    int wave = threadIdx.x >> 6, lane = threadIdx.x & 63;
    if (lane == 0) { st[wave] = t_s; sc[wave] = c_s; }
    __syncthreads();
    if (threadIdx.x == 0) {
        atomicAdd(&acc[1], st[0] + st[1] + st[2] + st[3]);
        atomicAdd(&acc[2], sc[0] + sc[1] + sc[2] + sc[3]);
    }
}

// ---------------------------------------------------------------------------
// pdist + sorted-window match + homology sum.
// Block b handles rows b and 510-b (each block: exactly 512 pairs, balanced;
// block 255 handles row 255 alone, 256 pairs).
// Match test: windows sorted by death => lo[] and hi[] both increasing =>
// pd in ANY window  <=>  hi[ub-1] >= pd, ub = #lo <= pd (9-step bsearch).
// ---------------------------------------------------------------------------
__device__ __forceinline__ double pair_val(const double* __restrict__ yrow_s,
                                           const double* __restrict__ yj,
                                           const double* __restrict__ slo,
                                           const double* __restrict__ shi) {
    double s = 0.0;
    #pragma unroll
    for (int d = 0; d < OUT_; d += 2) {
        double2 v = *(const double2*)(yj + d);
        double d0 = yrow_s[d]     - v.x;
        double d1 = yrow_s[d + 1] - v.y;
        s = fma(d0, d0, s);
        s = fma(d1, d1, s);
    }
    double pd = sqrt(s);
    // upper-bound binary search on slo[0..511] (padded with 1e300)
    int pos = 0;
    #pragma unroll
    for (int step = NSORT / 2; step; step >>= 1) {
        if (slo[pos + step - 1] <= pd) pos += step;
    }
    bool m = (pos > 0) && (shi[pos - 1] >= pd);
    return m ? pd : 0.0;
}

__global__ __launch_bounds__(256) void pdist_k(const double* __restrict__ y,
                                               const double* __restrict__ lo,
                                               const double* __restrict__ hi,
                                               double* __restrict__ acc) {
    const int b = blockIdx.x;   // 0..255
    const int t = threadIdx.x;
    const int iA = b;
    const int iB = 510 - b;     // == iA when b == 255

    __shared__ double yA[OUT_], yB[OUT_];
    __shared__ double slo[NSORT], shi[NSORT];
    if (t < OUT_)            yA[t]        = y[(size_t)iA * OUT_ + t];
    else if (t < 2 * OUT_)   yB[t - OUT_] = y[(size_t)iB * OUT_ + (t - OUT_)];
    #pragma unroll
    for (int k = t; k < NSORT; k += 256) { slo[k] = lo[k]; shi[k] = hi[k]; }
    __syncthreads();

    double local = 0.0;
    for (int j = iA + 1 + t; j < B_; j += 256)
        local += pair_val(yA, y + (size_t)j * OUT_, slo, shi);
    if (iB != iA)
        for (int j = iB + 1 + t; j < B_; j += 256)
            local += pair_val(yB, y + (size_t)j * OUT_, slo, shi);

    for (int off = 32; off; off >>= 1) local += __shfl_down(local, off);
    __shared__ double sw[4];
    int wave = t >> 6, lane = t & 63;
    if (lane == 0) sw[wave] = local;
    __syncthreads();
    if (t == 0) {
        double s = sw[0] + sw[1] + sw[2] + sw[3];
        if (s != 0.0) atomicAdd(&acc[0], s);
    }
}

// ---------------------------------------------------------------------------
// finalize: loss = mean_sq + hom + 0.01*compact
// ---------------------------------------------------------------------------
__global__ void fin_k(const double* __restrict__ acc, float* __restrict__ out) {
    out[0] = (float)(acc[1] / (double)(B_ * OUT_) + acc[0] + 0.01 * acc[2]);
}

extern "C" void kernel_launch(void* const* d_in, const int* in_sizes, int n_in,
                              void* d_out, int out_size, void* d_ws, size_t ws_size,
                              hipStream_t stream) {
    const float* batch  = (const float*)d_in[0];
    const float* target = (const float*)d_in[1];
    const float* W1     = (const float*)d_in[2];
    const float* b1     = (const float*)d_in[3];
    const float* W2     = (const float*)d_in[4];
    const float* b2     = (const float*)d_in[5];
    const float* W3     = (const float*)d_in[6];
    const float* b3     = (const float*)d_in[7];
    const float* Wout   = (const float*)d_in[8];
    const float* bout   = (const float*)d_in[9];
    const float* deaths = (const float*)d_in[10];
    float* out = (float*)d_out;

    double* hA  = (double*)d_ws;            // 512*512
    double* hB  = hA + (size_t)B_ * H_;     // 512*512
    double* yv  = hB + (size_t)B_ * H_;     // 512*64
    double* cm  = yv + (size_t)B_ * OUT_;   // 64
    double* lo  = cm + OUT_;                // 512 (sorted, padded)
    double* hi  = lo + NSORT;               // 512
    double* acc = hi + NSORT;               // 3

    init_k<<<dim3(1), dim3(NSORT), 0, stream>>>(deaths, lo, hi, acc);

    dim3 blk(16, 16);
    gemm_k<float, true><<<dim3(H_ / 32, B_ / 32), blk, 0, stream>>>(
        batch, W1, b1, hA, B_, H_, IN_);
    gemm_k<double, true><<<dim3(H_ / 32, B_ / 32), blk, 0, stream>>>(
        hA, W2, b2, hB, B_, H_, H_);
    gemm_k<double, true><<<dim3(H_ / 32, B_ / 32), blk, 0, stream>>>(
        hB, W3, b3, hA, B_, H_, H_);
    gemm_k<double, false><<<dim3(OUT_ / 32, B_ / 32), blk, 0, stream>>>(
        hA, Wout, bout, yv, B_, OUT_, H_);

    colmean_k<<<dim3(OUT_), dim3(64), 0, stream>>>(yv, cm);
    tc_k<<<dim3((B_ * OUT_) / 256), dim3(256), 0, stream>>>(target, yv, cm, acc);
    pdist_k<<<dim3(B_ - 1 - 255), dim3(256), 0, stream>>>(yv, lo, hi, acc);
    fin_k<<<dim3(1), dim3(1), 0, stream>>>(acc, out);
}

// Round 3
// 195.082 us; speedup vs baseline: 1.6025x; 1.1036x over previous
//
#include <hip/hip_runtime.h>

#define B_    512
#define IN_   256
#define H_    512
#define OUT_  64
#define NDEATH (B_ - 1)
#define NSORT  512          // NDEATH padded to pow2 for bitonic sort / bsearch
#define RTOL_ 1e-6
#define ATOL_ 1e-8

typedef __attribute__((ext_vector_type(4))) double d4_t;

// ---------------------------------------------------------------------------
// init: bitonic-sort deaths, emit sorted tolerance windows, zero accumulators.
// acc[0]=homology_sum, acc[1]=target_sq_sum, acc[2]=compactness_sum
// ---------------------------------------------------------------------------
__global__ __launch_bounds__(NSORT) void init_k(const float* __restrict__ deaths,
                                                double* __restrict__ lo,
                                                double* __restrict__ hi,
                                                double* __restrict__ acc) {
    __shared__ double sd[NSORT];
    const int t = threadIdx.x;
    sd[t] = (t < NDEATH) ? (double)deaths[t] : 1e300;
    __syncthreads();
    for (int k = 2; k <= NSORT; k <<= 1) {
        for (int j = k >> 1; j > 0; j >>= 1) {
            int ixj = t ^ j;
            if (ixj > t) {
                double a = sd[t], b = sd[ixj];
                bool up = ((t & k) == 0);
                if ((a > b) == up) { sd[t] = b; sd[ixj] = a; }
            }
            __syncthreads();
        }
    }
    double d = sd[t];
    double w = ATOL_ + RTOL_ * fabs(d);
    lo[t] = d - w;
    hi[t] = d + w;
    if (t < 3) acc[t] = 0.0;
}

// ---------------------------------------------------------------------------
// f64 MFMA GEMM: C[M,N] = act(A[M,K] @ W[K,N] + bias[N]).
// Block = 256 threads (4 waves), 32x32 output tile, each wave one 16x16 MFMA
// accumulator via v_mfma_f64_16x16x4_f64. K-tile 16, double-buffered LDS with
// register prefetch. Fragment layouts = verified gfx950 16x16 pattern:
//   A: [m=lane&15][k=lane>>4]  B: [k=lane>>4][n=lane&15]
//   D: col=lane&15, row=(lane>>4)*4+reg
// ---------------------------------------------------------------------------
template <typename TIN, bool RELU>
__global__ __launch_bounds__(256) void gemm_k(const TIN* __restrict__ A,
                                              const float* __restrict__ W,
                                              const float* __restrict__ bias,
                                              double* __restrict__ C,
                                              int M, int N, int K) {
    __shared__ double As[2][16][33];   // [buf][kk][mm]
    __shared__ double Ws[2][16][33];   // [buf][kk][nn]
    const int t    = threadIdx.x;
    const int lane = t & 63;
    const int wave = t >> 6;
    const int wm   = wave & 1, wn = wave >> 1;
    const int row0 = blockIdx.y * 32, col0 = blockIdx.x * 32;

    // staging indices: 2 elements each of A-tile (32x16) and W-tile (16x32)
    const int amm0 = t >> 4, akk = t & 15;          // e=t       -> (mm, kk)
    const int amm1 = amm0 + 16;                     // e=t+256
    const int wkk0 = t >> 5, wnn = t & 31;          // e=t       -> (kk, nn)
    const int wkk1 = wkk0 + 8;                      // e=t+256

    const int nkt = K >> 4;

    // prefetch + stage kt = 0
    double a0 = (double)A[(size_t)(row0 + amm0) * K + akk];
    double a1 = (double)A[(size_t)(row0 + amm1) * K + akk];
    double w0 = (double)W[(size_t)wkk0 * N + col0 + wnn];
    double w1 = (double)W[(size_t)wkk1 * N + col0 + wnn];
    As[0][akk][amm0] = a0;  As[0][akk][amm1] = a1;
    Ws[0][wkk0][wnn] = w0;  Ws[0][wkk1][wnn] = w1;
    __syncthreads();

    d4_t acc = {0.0, 0.0, 0.0, 0.0};
    const int mrow = wm * 16 + (lane & 15);
    const int ncol = wn * 16 + (lane & 15);
    const int kq   = lane >> 4;

    for (int kt = 0; kt < nkt; ++kt) {
        const int cur = kt & 1;
        if (kt + 1 < nkt) {               // issue next-tile global loads early
            const int k0 = (kt + 1) << 4;
            a0 = (double)A[(size_t)(row0 + amm0) * K + k0 + akk];
            a1 = (double)A[(size_t)(row0 + amm1) * K + k0 + akk];
            w0 = (double)W[(size_t)(k0 + wkk0) * N + col0 + wnn];
            w1 = (double)W[(size_t)(k0 + wkk1) * N + col0 + wnn];
        }
        #pragma unroll
        for (int ks = 0; ks < 4; ++ks) {
            double av = As[cur][ks * 4 + kq][mrow];
            double bv = Ws[cur][ks * 4 + kq][ncol];
            acc = __builtin_amdgcn_mfma_f64_16x16x4f64(av, bv, acc, 0, 0, 0);
        }
        __syncthreads();                  // everyone done reading buf `cur`
        if (kt + 1 < nkt) {
            const int nxt = cur ^ 1;
            As[nxt][akk][amm0] = a0;  As[nxt][akk][amm1] = a1;
            Ws[nxt][wkk0][wnn] = w0;  Ws[nxt][wkk1][wnn] = w1;
        }
        __syncthreads();                  // buf `nxt` filled
    }

    #pragma unroll
    for (int r = 0; r < 4; ++r) {
        int row = row0 + wm * 16 + (lane >> 4) * 4 + r;
        int col = col0 + wn * 16 + (lane & 15);
        double v = acc[r] + (double)bias[col];
        if (RELU) v = v > 0.0 ? v : 0.0;
        C[(size_t)row * N + col] = v;
    }
}

// ---------------------------------------------------------------------------
// fused column-mean + target-MSE-sum + compactness-sum. One block per column.
// ---------------------------------------------------------------------------
__global__ __launch_bounds__(256) void mc_k(const float* __restrict__ target,
                                            const double* __restrict__ y,
                                            double* __restrict__ acc) {
    const int c = blockIdx.x;      // column 0..63
    const int t = threadIdx.x;
    const int wave = t >> 6, lane = t & 63;
    double v0 = y[(size_t)t * OUT_ + c];
    double v1 = y[(size_t)(t + 256) * OUT_ + c];
    double s = v0 + v1;
    for (int off = 32; off; off >>= 1) s += __shfl_down(s, off);
    __shared__ double sw[4];
    __shared__ double smean;
    if (lane == 0) sw[wave] = s;
    __syncthreads();
    if (t == 0) smean = (sw[0] + sw[1] + sw[2] + sw[3]) / (double)B_;
    __syncthreads();
    double m = smean;
    double d0 = (double)target[(size_t)t * OUT_ + c] - v0;
    double d1 = (double)target[(size_t)(t + 256) * OUT_ + c] - v1;
    double t_s = d0 * d0 + d1 * d1;
    double c_s = fabs(v0 - m) + fabs(v1 - m);
    for (int off = 32; off; off >>= 1) {
        t_s += __shfl_down(t_s, off);
        c_s += __shfl_down(c_s, off);
    }
    __shared__ double st[4], sc[4];
    if (lane == 0) { st[wave] = t_s; sc[wave] = c_s; }
    __syncthreads();
    if (t == 0) {
        atomicAdd(&acc[1], st[0] + st[1] + st[2] + st[3]);
        atomicAdd(&acc[2], sc[0] + sc[1] + sc[2] + sc[3]);
    }
}

// ---------------------------------------------------------------------------
// pdist + sorted-window match + homology sum. Block b: rows b and 510-b
// (512 pairs each, balanced). Match: lo/hi both increasing => pd in any
// window <=> hi[ub-1] >= pd, ub from 9-step bsearch on lo.
// ---------------------------------------------------------------------------
__device__ __forceinline__ double pair_val(const double* __restrict__ yrow_s,
                                           const double* __restrict__ yj,
                                           const double* __restrict__ slo,
                                           const double* __restrict__ shi) {
    double s = 0.0;
    #pragma unroll
    for (int d = 0; d < OUT_; d += 2) {
        double2 v = *(const double2*)(yj + d);
        double d0 = yrow_s[d]     - v.x;
        double d1 = yrow_s[d + 1] - v.y;
        s = fma(d0, d0, s);
        s = fma(d1, d1, s);
    }
    double pd = sqrt(s);
    int pos = 0;
    #pragma unroll
    for (int step = NSORT / 2; step; step >>= 1) {
        if (slo[pos + step - 1] <= pd) pos += step;
    }
    bool m = (pos > 0) && (shi[pos - 1] >= pd);
    return m ? pd : 0.0;
}

__global__ __launch_bounds__(256) void pdist_k(const double* __restrict__ y,
                                               const double* __restrict__ lo,
                                               const double* __restrict__ hi,
                                               double* __restrict__ acc) {
    const int b = blockIdx.x;   // 0..255
    const int t = threadIdx.x;
    const int iA = b;
    const int iB = 510 - b;     // == iA when b == 255

    __shared__ double yA[OUT_], yB[OUT_];
    __shared__ double slo[NSORT], shi[NSORT];
    if (t < OUT_)            yA[t]        = y[(size_t)iA * OUT_ + t];
    else if (t < 2 * OUT_)   yB[t - OUT_] = y[(size_t)iB * OUT_ + (t - OUT_)];
    #pragma unroll
    for (int k = t; k < NSORT; k += 256) { slo[k] = lo[k]; shi[k] = hi[k]; }
    __syncthreads();

    double local = 0.0;
    for (int j = iA + 1 + t; j < B_; j += 256)
        local += pair_val(yA, y + (size_t)j * OUT_, slo, shi);
    if (iB != iA)
        for (int j = iB + 1 + t; j < B_; j += 256)
            local += pair_val(yB, y + (size_t)j * OUT_, slo, shi);

    for (int off = 32; off; off >>= 1) local += __shfl_down(local, off);
    __shared__ double sw[4];
    int wave = t >> 6, lane = t & 63;
    if (lane == 0) sw[wave] = local;
    __syncthreads();
    if (t == 0) {
        double s = sw[0] + sw[1] + sw[2] + sw[3];
        if (s != 0.0) atomicAdd(&acc[0], s);
    }
}

// ---------------------------------------------------------------------------
// finalize: loss = mean_sq + hom + 0.01*compact
// ---------------------------------------------------------------------------
__global__ void fin_k(const double* __restrict__ acc, float* __restrict__ out) {
    out[0] = (float)(acc[1] / (double)(B_ * OUT_) + acc[0] + 0.01 * acc[2]);
}

extern "C" void kernel_launch(void* const* d_in, const int* in_sizes, int n_in,
                              void* d_out, int out_size, void* d_ws, size_t ws_size,
                              hipStream_t stream) {
    const float* batch  = (const float*)d_in[0];
    const float* target = (const float*)d_in[1];
    const float* W1     = (const float*)d_in[2];
    const float* b1     = (const float*)d_in[3];
    const float* W2     = (const float*)d_in[4];
    const float* b2     = (const float*)d_in[5];
    const float* W3     = (const float*)d_in[6];
    const float* b3     = (const float*)d_in[7];
    const float* Wout   = (const float*)d_in[8];
    const float* bout   = (const float*)d_in[9];
    const float* deaths = (const float*)d_in[10];
    float* out = (float*)d_out;

    double* hA  = (double*)d_ws;            // 512*512
    double* hB  = hA + (size_t)B_ * H_;     // 512*512
    double* yv  = hB + (size_t)B_ * H_;     // 512*64
    double* cm  = yv + (size_t)B_ * OUT_;   // (unused, kept for layout)
    double* lo  = cm + OUT_;                // 512 (sorted, padded)
    double* hi  = lo + NSORT;               // 512
    double* acc = hi + NSORT;               // 3

    init_k<<<dim3(1), dim3(NSORT), 0, stream>>>(deaths, lo, hi, acc);

    gemm_k<float, true><<<dim3(H_ / 32, B_ / 32), dim3(256), 0, stream>>>(
        batch, W1, b1, hA, B_, H_, IN_);
    gemm_k<double, true><<<dim3(H_ / 32, B_ / 32), dim3(256), 0, stream>>>(
        hA, W2, b2, hB, B_, H_, H_);
    gemm_k<double, true><<<dim3(H_ / 32, B_ / 32), dim3(256), 0, stream>>>(
        hB, W3, b3, hA, B_, H_, H_);
    gemm_k<double, false><<<dim3(OUT_ / 32, B_ / 32), dim3(256), 0, stream>>>(
        hA, Wout, bout, yv, B_, OUT_, H_);

    mc_k<<<dim3(OUT_), dim3(256), 0, stream>>>(target, yv, acc);
    pdist_k<<<dim3(256), dim3(256), 0, stream>>>(yv, lo, hi, acc);
    fin_k<<<dim3(1), dim3(1), 0, stream>>>(acc, out);
}